// Round 1
// baseline (147.359 us; speedup 1.0000x reference)
//
#include <hip/hip_runtime.h>

#define GAMMA 0.99f
#define LAM   0.95f

constexpr int BLOCK = 256;
constexpr int CHUNK = 8;           // timesteps per thread; requires T == BLOCK*CHUNK
constexpr int NWAVES = BLOCK / 64;

// One block per row (B blocks). Thread i owns columns [i*CHUNK, i*CHUNK+CHUNK).
// Backward linear recurrence parallelized via affine composition:
//   g[t] = delta[t] + c[t]*g[t+1]  ==>  chunk maps incoming g to a + m*g.
__global__ __launch_bounds__(BLOCK) void gae_scan_kernel(
    const float* __restrict__ rewards,
    const float* __restrict__ values,
    const float* __restrict__ next_value,
    const int*   __restrict__ done,
    float* __restrict__ adv_out,
    float* __restrict__ ret_out,
    int T)
{
    const int row  = blockIdx.x;
    const int tid  = threadIdx.x;
    const int lane = tid & 63;
    const int wave = tid >> 6;

    const long rowbase = (long)row * T;
    const int  col0    = tid * CHUNK;

    // ---- vectorized loads of this thread's chunk ----
    float r[CHUNK], v[CHUNK];
    const float4* r4 = reinterpret_cast<const float4*>(rewards + rowbase + col0);
    const float4* v4 = reinterpret_cast<const float4*>(values  + rowbase + col0);
    float4 ra = r4[0], rb = r4[1];
    float4 va = v4[0], vb = v4[1];
    r[0]=ra.x; r[1]=ra.y; r[2]=ra.z; r[3]=ra.w;
    r[4]=rb.x; r[5]=rb.y; r[6]=rb.z; r[7]=rb.w;
    v[0]=va.x; v[1]=va.y; v[2]=va.z; v[3]=va.w;
    v[4]=vb.x; v[5]=vb.y; v[6]=vb.z; v[7]=vb.w;

    // value feeding the LAST element of this chunk (values[t+1], or bootstrap)
    const float vnext_last = (col0 + CHUNK < T) ? values[rowbase + col0 + CHUNK]
                                                : next_value[row];

    // ---- delta[t] and c[t] ----
    float delta[CHUNK], c[CHUNK];
#pragma unroll
    for (int j = 0; j < CHUNK; ++j) {
        const int tcol = col0 + j;
        const int dcol = (tcol + 1 < T) ? (tcol + 1) : (T - 1);
        const float nnt = 1.0f - (float)done[rowbase + dcol];
        const float nv  = (j < CHUNK - 1) ? v[j + 1] : vnext_last;
        delta[j] = r[j] + GAMMA * nv * nnt - v[j];
        c[j]     = (GAMMA * LAM) * nnt;
    }

    // ---- per-thread affine composition over the chunk (backward) ----
    // After loop: g_at_chunk_start = a + m * g_incoming
    float a = 0.0f, m = 1.0f;
#pragma unroll
    for (int j = CHUNK - 1; j >= 0; --j) {
        a = delta[j] + c[j] * a;
        m = c[j] * m;
    }

    // ---- wave-level inclusive SUFFIX scan of affine fns (self ∘ higher-lane) ----
    float sa = a, sm = m;
#pragma unroll
    for (int d = 1; d < 64; d <<= 1) {
        float oa = __shfl_down(sa, d);
        float om = __shfl_down(sm, d);
        if (lane + d < 64) { sa = sa + sm * oa; sm = sm * om; }
    }
    // exclusive-within-wave (function of all higher lanes in this wave)
    float ea = __shfl_down(sa, 1);
    float em = __shfl_down(sm, 1);
    if (lane == 63) { ea = 0.0f; em = 1.0f; }

    // ---- cross-wave composition via LDS (wave totals live in lane 0's sa/sm) ----
    __shared__ float lds_a[NWAVES];
    __shared__ float lds_m[NWAVES];
    if (lane == 0) { lds_a[wave] = sa; lds_m[wave] = sm; }
    __syncthreads();

    float g = 0.0f;                       // gae entering from waves above this one
    for (int j = NWAVES - 1; j > wave; --j)
        g = lds_a[j] + lds_m[j] * g;
    float gin = ea + em * g;              // gae entering this thread's chunk

    // ---- replay: exact sequential recurrence over the chunk ----
    float adv[CHUNK];
#pragma unroll
    for (int j = CHUNK - 1; j >= 0; --j) {
        gin = delta[j] + c[j] * gin;
        adv[j] = gin;
    }

    // ---- vectorized stores: advantages, then returns = adv + values ----
    float4* a4 = reinterpret_cast<float4*>(adv_out + rowbase + col0);
    float4* t4 = reinterpret_cast<float4*>(ret_out + rowbase + col0);
    a4[0] = make_float4(adv[0], adv[1], adv[2], adv[3]);
    a4[1] = make_float4(adv[4], adv[5], adv[6], adv[7]);
    t4[0] = make_float4(adv[0] + v[0], adv[1] + v[1], adv[2] + v[2], adv[3] + v[3]);
    t4[1] = make_float4(adv[4] + v[4], adv[5] + v[5], adv[6] + v[6], adv[7] + v[7]);
}

// Fallback for shapes where T != BLOCK*CHUNK: one thread per row, sequential.
__global__ void gae_naive_kernel(
    const float* __restrict__ rewards,
    const float* __restrict__ values,
    const float* __restrict__ next_value,
    const int*   __restrict__ done,
    float* __restrict__ adv_out,
    float* __restrict__ ret_out,
    int B, int T)
{
    int row = blockIdx.x * blockDim.x + threadIdx.x;
    if (row >= B) return;
    long base = (long)row * T;
    float g = 0.0f;
    for (int t = T - 1; t >= 0; --t) {
        int dcol = (t + 1 < T) ? (t + 1) : (T - 1);
        float nnt = 1.0f - (float)done[base + dcol];
        float nv  = (t + 1 < T) ? values[base + t + 1] : next_value[row];
        float dl  = rewards[base + t] + GAMMA * nv * nnt - values[base + t];
        g = dl + (GAMMA * LAM) * nnt * g;
        adv_out[base + t] = g;
        ret_out[base + t] = g + values[base + t];
    }
}

extern "C" void kernel_launch(void* const* d_in, const int* in_sizes, int n_in,
                              void* d_out, int out_size, void* d_ws, size_t ws_size,
                              hipStream_t stream) {
    const float* rewards    = (const float*)d_in[0];
    const float* values     = (const float*)d_in[1];
    const float* next_value = (const float*)d_in[2];
    const int*   done       = (const int*)d_in[3];

    const int B = in_sizes[2];               // next_value is [B]
    const int T = in_sizes[0] / B;           // rewards is [B, T]

    float* adv = (float*)d_out;
    float* ret = adv + (long)B * T;

    if (T == BLOCK * CHUNK) {
        gae_scan_kernel<<<B, BLOCK, 0, stream>>>(
            rewards, values, next_value, done, adv, ret, T);
    } else {
        gae_naive_kernel<<<(B + 255) / 256, 256, 0, stream>>>(
            rewards, values, next_value, done, adv, ret, B, T);
    }
}